// Round 1
// baseline (166.511 us; speedup 1.0000x reference)
//
#include <hip/hip_runtime.h>
#include <hip/hip_bf16.h>

// Problem constants
#define N_ATOMS 262144
#define B_SZ    64
#define H_DIM   256
#define R_DIM   512

typedef __attribute__((ext_vector_type(8))) short bf16x8;
typedef __attribute__((ext_vector_type(4))) float f32x4;

static __device__ __forceinline__ short f2bf(float f) {
  unsigned u = __builtin_bit_cast(unsigned, f);
  u = (u + 0x7FFFu + ((u >> 16) & 1u)) >> 16;   // RNE
  return (short)u;
}

// ---------------------------------------------------------------------------
// Kernel 0: convert Wl[:, :256] (the h-part of the linear weight) into bf16,
// laid out in exact MFMA B-fragment order:
//   Bbf[((ct*8 + ks)*64 + lane)*8 + j]  holds  Wl[o][k]
//   with o = ct*16 + (lane&15),  k = ks*32 + (lane>>4)*8 + j
// so the main kernel's per-wave B loads are single coalesced 16B reads.
// ---------------------------------------------------------------------------
__global__ void convert_B_kernel(const float* __restrict__ Wl,
                                 short* __restrict__ Bbf) {
  int idx  = blockIdx.x * 256 + threadIdx.x;        // 0..65535
  int j    = idx & 7;
  int lane = (idx >> 3) & 63;
  int ks   = (idx >> 9) & 7;
  int ct   = idx >> 12;
  int o    = ct * 16 + (lane & 15);
  int k    = ks * 32 + ((lane >> 4) << 3) + j;
  Bbf[idx] = f2bf(Wl[o * (2 * H_DIM) + k]);
}

// ---------------------------------------------------------------------------
// Kernel 1: pooled[b][o] = bl[o] + sum_j ret[b][j] * Wl[o][256+j]
//           ret[b][j]    = bp[j] + sum_r mean_k(ret_feat[b][k][r]) * Wp[j][r]
// All fp32 (exact w.r.t. reference). One block per batch element.
// ---------------------------------------------------------------------------
__global__ void pooled_kernel(const float* __restrict__ rf,
                              const float* __restrict__ Wp,
                              const float* __restrict__ bp,
                              const float* __restrict__ Wl,
                              const float* __restrict__ bl,
                              float* __restrict__ pooled) {
  __shared__ float meanr[R_DIM];
  __shared__ float retj[H_DIM];
  int b = blockIdx.x;
  int t = threadIdx.x;          // 256 threads

  // mean over K=16
  for (int r = t; r < R_DIM; r += 256) {
    float s = 0.f;
    const float* p = rf + (long)b * 16 * R_DIM + r;
#pragma unroll
    for (int k = 0; k < 16; ++k) s += p[k * R_DIM];
    meanr[r] = s * (1.f / 16.f);
  }
  __syncthreads();

  // ret[j] = bp[j] + meanr . Wp[j,:]
  {
    float s = bp[t];
    const float* w = Wp + (long)t * R_DIM;
    for (int r = 0; r < R_DIM; ++r) s += meanr[r] * w[r];
    retj[t] = s;
  }
  __syncthreads();

  // pooled[o] = bl[o] + retj . Wl[o, 256:512]
  {
    float s = bl[t];
    const float* w = Wl + (long)t * (2 * H_DIM) + H_DIM;
    for (int j = 0; j < H_DIM; ++j) s += retj[j] * w[j];
    pooled[(long)b * H_DIM + t] = s;
  }
}

// ---------------------------------------------------------------------------
// Kernel 2: out[n][o] = sum_k h[n][k] * Wl[o][k]  +  pooled[batch[n]][o]
// 1024 threads = 16 waves; wave w owns output columns [16w, 16w+16).
// Each block handles 64 rows; A tile staged in LDS (bf16, XOR-swizzled),
// B strip held in registers (8 k-step fragments), mfma_f32_16x16x32_bf16.
// ---------------------------------------------------------------------------
__global__ __launch_bounds__(1024, 1) void gemm_kernel(
    const float* __restrict__ h, const short* __restrict__ Bbf,
    const float* __restrict__ pooled, const int* __restrict__ batch,
    float* __restrict__ out) {
  __shared__ short As[64 * 256];   // 32 KiB bf16, swizzled
  int t    = threadIdx.x;
  int lane = t & 63;
  int w    = t >> 6;               // wave id 0..15 = column tile
  long m0  = (long)blockIdx.x * 64;

  // --- load this wave's B strip (8 k-steps x 16B, perfectly coalesced) ---
  bf16x8 bfrag[8];
#pragma unroll
  for (int ks = 0; ks < 8; ++ks)
    bfrag[ks] = *(const bf16x8*)(Bbf + (((w * 8 + ks) * 64 + lane) << 3));

  // --- stage A tile: 64 rows x 256 cols f32 -> bf16 in LDS ---
  {
    int r  = t >> 4;               // 0..63
    int c0 = (t & 15) << 4;        // 0,16,...,240
    const f32x4* src = (const f32x4*)(h + (m0 + r) * H_DIM + c0);
    f32x4 v0 = src[0], v1 = src[1], v2 = src[2], v3 = src[3];
    bf16x8 lo, hi;
    lo[0] = f2bf(v0[0]); lo[1] = f2bf(v0[1]); lo[2] = f2bf(v0[2]); lo[3] = f2bf(v0[3]);
    lo[4] = f2bf(v1[0]); lo[5] = f2bf(v1[1]); lo[6] = f2bf(v1[2]); lo[7] = f2bf(v1[3]);
    hi[0] = f2bf(v2[0]); hi[1] = f2bf(v2[1]); hi[2] = f2bf(v2[2]); hi[3] = f2bf(v2[3]);
    hi[4] = f2bf(v3[0]); hi[5] = f2bf(v3[1]); hi[6] = f2bf(v3[2]); hi[7] = f2bf(v3[3]);
    int base = (r << 9) + (c0 << 1);      // byte offset, 32B aligned
    int swz  = (r & 7) << 4;
    *(bf16x8*)((char*)As + ( base        ^ swz)) = lo;
    *(bf16x8*)((char*)As + ((base + 16)  ^ swz)) = hi;
  }
  __syncthreads();

  // --- 4 row-tiles of 16, MFMA over 8 k-steps each ---
  int o       = (w << 4) + (lane & 15);
  int arow    = lane & 15;
  int kbyte   = (lane >> 4) << 4;        // (lane>>4)*8 elems * 2B
#pragma unroll
  for (int rt = 0; rt < 4; ++rt) {
    f32x4 acc = {0.f, 0.f, 0.f, 0.f};
    int row = rt * 16 + arow;
    int swz = (row & 7) << 4;
#pragma unroll
    for (int ks = 0; ks < 8; ++ks) {
      int off = ((row << 9) + (ks << 6) + kbyte) ^ swz;
      bf16x8 afrag = *(const bf16x8*)((const char*)As + off);
      acc = __builtin_amdgcn_mfma_f32_16x16x32_bf16(afrag, bfrag[ks], acc, 0, 0, 0);
    }
    // epilogue: C/D layout col=lane&15, row=(lane>>4)*4+reg
    long rbase = m0 + rt * 16 + ((lane >> 4) << 2);
#pragma unroll
    for (int r = 0; r < 4; ++r) {
      long rowg = rbase + r;
      int  b    = batch[rowg];
      out[rowg * H_DIM + o] = acc[r] + pooled[b * H_DIM + o];
    }
  }
}

// ---------------------------------------------------------------------------
extern "C" void kernel_launch(void* const* d_in, const int* in_sizes, int n_in,
                              void* d_out, int out_size, void* d_ws, size_t ws_size,
                              hipStream_t stream) {
  const float* h   = (const float*)d_in[0];
  const float* rf  = (const float*)d_in[1];
  const int*   bat = (const int*)d_in[2];
  const float* Wp  = (const float*)d_in[3];
  const float* bp  = (const float*)d_in[4];
  const float* Wl  = (const float*)d_in[5];
  const float* bl  = (const float*)d_in[6];
  float* out = (float*)d_out;

  float* pooled = (float*)d_ws;                          // 64*256*4 = 64 KiB
  short* Bbf    = (short*)((char*)d_ws + 64 * 1024);     // 128 KiB bf16

  convert_B_kernel<<<256, 256, 0, stream>>>(Wl, Bbf);
  pooled_kernel<<<B_SZ, 256, 0, stream>>>(rf, Wp, bp, Wl, bl, pooled);
  gemm_kernel<<<N_ATOMS / 64, 1024, 0, stream>>>(h, Bbf, pooled, bat, out);
}